// Round 1
// baseline (294.521 us; speedup 1.0000x reference)
//
#include <hip/hip_runtime.h>

#define NB 4
#define NC 256
#define NH 128
#define NW 256
#define ND 48
#define NHW (NH * NW)
#define CC 32
#define NCHUNK (NC / CC)
#define RW (NW + ND)   /* 304 */

__device__ inline void async16(void* lds, const void* g) {
  __builtin_amdgcn_global_load_lds(
      (const __attribute__((address_space(1))) void*)g,
      (__attribute__((address_space(3))) void*)lds,
      16, 0, 0);
}

__global__ __launch_bounds__(256, 2)
void corr_vol_kernel(const float* __restrict__ Lf,
                     const float* __restrict__ Rf,
                     float* __restrict__ out) {
  __shared__ float Lt[CC][NW];   // 32 KB
  __shared__ float Rt[CC][RW];   // 38 KB
  __shared__ float nL[NW];
  __shared__ float nR[RW];

  const int tid  = threadIdx.x;
  const int lane = tid & 63;
  const int wv   = tid >> 6;          // wave id 0..3
  const int b    = blockIdx.x >> 7;   // /128
  const int h    = blockIdx.x & 127;

  const float* Lb = Lf + ((size_t)b * NC) * NHW + (size_t)h * NW;
  const float* Rb = Rf + ((size_t)b * NC) * NHW + (size_t)h * NW;

  // zero-fill the persistent left halo of Rt (w<0 region) and nR pad
  for (int idx = tid; idx < CC * ND; idx += 256) {
    Rt[idx / ND][idx % ND] = 0.0f;
  }
  if (tid < ND) nR[tid] = 0.0f;

  // thread tiling: 4 consecutive w, 12 consecutive i
  const int w0 = (tid & 63) << 2;     // 0..252, mult of 4
  const int i0 = (tid >> 6) * 12;     // 0,12,24,36
  const int rb = w0 + 36 - i0;        // 16B-aligned R read base (mult of 4)

  float acc[4][12];
  #pragma unroll
  for (int a = 0; a < 4; ++a)
    #pragma unroll
    for (int q = 0; q < 12; ++q) acc[a][q] = 0.0f;

  float l2 = 0.0f, r2 = 0.0f;

  for (int ch = 0; ch < NCHUNK; ++ch) {
    // ---- stage chunk: each wave stages 8 L rows + 8 R rows (1024B each) ----
    const size_t coff = (size_t)(ch * CC) * NHW;
    #pragma unroll
    for (int k = 0; k < 8; ++k) {
      const int cl = wv * 8 + k;
      const size_t go = coff + (size_t)cl * NHW + (size_t)(lane * 4);
      async16(&Lt[cl][0],  Lb + go);
      async16(&Rt[cl][ND], Rb + go);
    }
    __syncthreads();   // drains vmcnt (global_load_lds) + lds writes

    // ---- norm accumulation: thread t owns column t ----
    #pragma unroll 8
    for (int c = 0; c < CC; ++c) {
      const float lv = Lt[c][tid];
      const float rv = Rt[c][tid + ND];
      l2 = fmaf(lv, lv, l2);
      r2 = fmaf(rv, rv, r2);
    }

    // ---- main correlation: per channel 5x ds_read_b128 + 48 FMA ----
    #pragma unroll 4
    for (int c = 0; c < CC; ++c) {
      const float4 lv4 = *reinterpret_cast<const float4*>(&Lt[c][w0]);
      const float4 r0v = *reinterpret_cast<const float4*>(&Rt[c][rb]);
      const float4 r1v = *reinterpret_cast<const float4*>(&Rt[c][rb + 4]);
      const float4 r2v = *reinterpret_cast<const float4*>(&Rt[c][rb + 8]);
      const float4 r3v = *reinterpret_cast<const float4*>(&Rt[c][rb + 12]);
      const float ll[4] = {lv4.x, lv4.y, lv4.z, lv4.w};
      const float rr[16] = {r0v.x, r0v.y, r0v.z, r0v.w,
                            r1v.x, r1v.y, r1v.z, r1v.w,
                            r2v.x, r2v.y, r2v.z, r2v.w,
                            r3v.x, r3v.y, r3v.z, r3v.w};
      #pragma unroll
      for (int dw = 0; dw < 4; ++dw) {
        #pragma unroll
        for (int di = 0; di < 12; ++di) {
          // rr index = (w - i + 48) - rb = dw - di + 12  (in [1,15])
          acc[dw][di] = fmaf(ll[dw], rr[dw - di + 12], acc[dw][di]);
        }
      }
    }
    __syncthreads();   // protect LDS before next chunk overwrites
  }

  // ---- publish norms ----
  nL[tid] = l2;
  nR[tid + ND] = r2;
  __syncthreads();

  float invL[4];
  #pragma unroll
  for (int a = 0; a < 4; ++a)
    invL[a] = 1.0f / fmaxf(sqrtf(nL[w0 + a]), 1e-12f);

  // j = (w - i) + 48 = jb + dw - di, need dw-di in [-11,3] -> 15 values
  const int jb = w0 - i0 + ND;
  float invR[15];
  #pragma unroll
  for (int k = 0; k < 15; ++k)
    invR[k] = 1.0f / fmaxf(sqrtf(nR[jb - 11 + k]), 1e-12f);

  // ---- scale + write: 12 coalesced float4 stores per thread ----
  #pragma unroll
  for (int di = 0; di < 12; ++di) {
    const int i = i0 + di;
    float4 v;
    v.x = acc[0][di] * invL[0] * invR[0 - di + 11];
    v.y = acc[1][di] * invL[1] * invR[1 - di + 11];
    v.z = acc[2][di] * invL[2] * invR[2 - di + 11];
    v.w = acc[3][di] * invL[3] * invR[3 - di + 11];
    *reinterpret_cast<float4*>(out + ((size_t)(b * ND + i) * NH + h) * NW + w0) = v;
  }
}

extern "C" void kernel_launch(void* const* d_in, const int* in_sizes, int n_in,
                              void* d_out, int out_size, void* d_ws, size_t ws_size,
                              hipStream_t stream) {
  const float* Lf = (const float*)d_in[0];
  const float* Rf = (const float*)d_in[1];
  float* out = (float*)d_out;
  // grid: one block per (b, h) row
  dim3 grid(NB * NH);
  dim3 block(256);
  corr_vol_kernel<<<grid, block, 0, stream>>>(Lf, Rf, out);
}